// Round 1
// baseline (999.969 us; speedup 1.0000x reference)
//
#include <hip/hip_runtime.h>

// ---------------------------------------------------------------------------
// 3-layer GATv2 + classifier on MI355X. f32 everywhere (no-MFMA baseline).
// Pipeline per layer: xl = h@Wl+bl, xr = h@Wr+br (tiled f32 GEMM),
// per-edge logits e = lrelu(xl[src]+xr[dst])@att, then per-dst-node
// segment softmax + weighted sum + bias + relu (CSR, no atomics on features).
// ---------------------------------------------------------------------------

static constexpr int BM = 64, BN = 64, BK = 16;

__global__ __launch_bounds__(256) void gemm_bias_kernel(
    const float* __restrict__ A, const float* __restrict__ W,
    const float* __restrict__ bias, float* __restrict__ C,
    int M, int K, int F)
{
    __shared__ float As[BK][BM];
    __shared__ float Bs[BK][BN];
    const int t = threadIdx.x;
    const int bm = blockIdx.x, bn = blockIdx.y;
    const int ty = t >> 4, tx = t & 15;          // 16x16 threads, each 4x4 out
    const int rowBase = bm * BM;
    const int colBase = bn * BN;
    const int aRow = t & 63;                     // A tile: 64 rows x 16 k
    const int aK = (t >> 6) << 2;
    const int gARow = min(rowBase + aRow, M - 1);
    const int bRow = t >> 4;                     // B tile: 16 rows x 64 cols
    const int bCol = (t & 15) << 2;

    float acc[4][4] = {{0.f, 0.f, 0.f, 0.f}};

    for (int k0 = 0; k0 < K; k0 += BK) {
        float4 av = *(const float4*)&A[(size_t)gARow * K + k0 + aK];
        float4 bv = *(const float4*)&W[(size_t)(k0 + bRow) * F + colBase + bCol];
        As[aK + 0][aRow] = av.x;
        As[aK + 1][aRow] = av.y;
        As[aK + 2][aRow] = av.z;
        As[aK + 3][aRow] = av.w;
        *(float4*)&Bs[bRow][bCol] = bv;
        __syncthreads();
#pragma unroll
        for (int kk = 0; kk < BK; ++kk) {
            float4 a4 = *(const float4*)&As[kk][ty << 2];
            float4 b4 = *(const float4*)&Bs[kk][tx << 2];
            float ar[4] = {a4.x, a4.y, a4.z, a4.w};
            float br_[4] = {b4.x, b4.y, b4.z, b4.w};
#pragma unroll
            for (int i = 0; i < 4; ++i)
#pragma unroll
                for (int j = 0; j < 4; ++j)
                    acc[i][j] += ar[i] * br_[j];
        }
        __syncthreads();
    }

    float4 bias4 = *(const float4*)&bias[colBase + (tx << 2)];
    float bb[4] = {bias4.x, bias4.y, bias4.z, bias4.w};
#pragma unroll
    for (int i = 0; i < 4; ++i) {
        int r = rowBase + (ty << 2) + i;
        if (r < M) {
            float4 o;
            o.x = acc[i][0] + bb[0];
            o.y = acc[i][1] + bb[1];
            o.z = acc[i][2] + bb[2];
            o.w = acc[i][3] + bb[3];
            *(float4*)&C[(size_t)r * F + colBase + (tx << 2)] = o;
        }
    }
}

// --------------------------- CSR build kernels ------------------------------

__global__ void zero_ints_kernel(int* __restrict__ p, int n)
{
    int i = blockIdx.x * blockDim.x + threadIdx.x;
    if (i < n) p[i] = 0;
}

__device__ inline void edge_src_dst(const int* __restrict__ ei, int edge,
                                    int E_orig, int& src, int& dst)
{
    if (edge < E_orig) {
        src = ei[edge];
        dst = ei[E_orig + edge];
    } else {
        src = dst = edge - E_orig;   // self-loop
    }
}

__global__ void count_kernel(const int* __restrict__ ei, int E_orig, int E_tot,
                             int* __restrict__ counts)
{
    int e = blockIdx.x * blockDim.x + threadIdx.x;
    if (e >= E_tot) return;
    int src, dst;
    edge_src_dst(ei, e, E_orig, src, dst);
    atomicAdd(&counts[dst], 1);
}

__global__ __launch_bounds__(256) void scan_kernel(const int* __restrict__ counts, int n,
                                                   int* __restrict__ offsets,
                                                   int* __restrict__ cursor)
{
    __shared__ int part[256];
    const int t = threadIdx.x;
    const int chunk = (n + 255) >> 8;
    const int begin = t * chunk;
    const int end = min(begin + chunk, n);
    int s = 0;
    for (int i = begin; i < end; ++i) s += counts[i];
    part[t] = s;
    __syncthreads();
    for (int off = 1; off < 256; off <<= 1) {
        int v = (t >= off) ? part[t - off] : 0;
        __syncthreads();
        part[t] += v;
        __syncthreads();
    }
    int run = (t == 0) ? 0 : part[t - 1];
    for (int i = begin; i < end; ++i) {
        offsets[i] = run;
        cursor[i] = run;
        run += counts[i];
    }
    if (t == 255) offsets[n] = part[255];
}

__global__ void fill_kernel(const int* __restrict__ ei, int E_orig, int E_tot,
                            int* __restrict__ cursor,
                            int* __restrict__ csr_src, int* __restrict__ csr_eid)
{
    int e = blockIdx.x * blockDim.x + threadIdx.x;
    if (e >= E_tot) return;
    int src, dst;
    edge_src_dst(ei, e, E_orig, src, dst);
    int pos = atomicAdd(&cursor[dst], 1);
    csr_src[pos] = src;
    csr_eid[pos] = e;
}

// --------------------------- edge logits ------------------------------------

__global__ __launch_bounds__(256) void edge_logits_kernel(
    const float* __restrict__ xl, const float* __restrict__ xr,
    const float* __restrict__ att, const int* __restrict__ ei,
    int E_orig, int E_tot, int F, float* __restrict__ e_out)
{
    int edge = blockIdx.x * 4 + (threadIdx.x >> 6);
    int lane = threadIdx.x & 63;
    if (edge >= E_tot) return;
    int src, dst;
    edge_src_dst(ei, edge, E_orig, src, dst);
    float acc = 0.f;
    const float* xls = xl + (size_t)src * F;
    const float* xrd = xr + (size_t)dst * F;
    for (int f = lane; f < F; f += 64) {
        float m = xls[f] + xrd[f];
        m = (m >= 0.f) ? m : 0.2f * m;
        acc += m * att[f];
    }
#pragma unroll
    for (int off = 32; off; off >>= 1) acc += __shfl_xor(acc, off);
    if (lane == 0) e_out[edge] = acc;
}

// ------------------- per-node softmax + aggregate + relu --------------------

__global__ __launch_bounds__(256) void aggregate_kernel(
    const float* __restrict__ xl, const float* __restrict__ e,
    const int* __restrict__ offsets, const int* __restrict__ csr_src,
    const int* __restrict__ csr_eid, const float* __restrict__ bias,
    float* __restrict__ out, int F)
{
    const int nIdx = blockIdx.x;
    const int t = threadIdx.x;
    const int start = offsets[nIdx], end = offsets[nIdx + 1];
    __shared__ float red[256];

    // pass A: segment max
    float lmax = -1e30f;
    for (int i = start + t; i < end; i += 256) lmax = fmaxf(lmax, e[csr_eid[i]]);
    red[t] = lmax;
    __syncthreads();
    for (int off = 128; off; off >>= 1) {
        if (t < off) red[t] = fmaxf(red[t], red[t + off]);
        __syncthreads();
    }
    const float emax = red[0];
    __syncthreads();

    // pass B: denom
    float lsum = 0.f;
    for (int i = start + t; i < end; i += 256) lsum += __expf(e[csr_eid[i]] - emax);
    red[t] = lsum;
    __syncthreads();
    for (int off = 128; off; off >>= 1) {
        if (t < off) red[t] += red[t + off];
        __syncthreads();
    }
    const float inv = 1.0f / red[0];
    __syncthreads();

    // pass C: weighted accumulate
    const int nf4 = F >> 2;
    float4 acc = {0.f, 0.f, 0.f, 0.f};
    for (int i = start; i < end; ++i) {
        int src = csr_src[i];
        float w = __expf(e[csr_eid[i]] - emax) * inv;
        if (t < nf4) {
            float4 v = *(const float4*)&xl[(size_t)src * F + (t << 2)];
            acc.x += w * v.x;
            acc.y += w * v.y;
            acc.z += w * v.z;
            acc.w += w * v.w;
        }
    }
    if (t < nf4) {
        float4 bv = *(const float4*)&bias[t << 2];
        float4 o;
        o.x = fmaxf(acc.x + bv.x, 0.f);
        o.y = fmaxf(acc.y + bv.y, 0.f);
        o.z = fmaxf(acc.z + bv.z, 0.f);
        o.w = fmaxf(acc.w + bv.w, 0.f);
        *(float4*)&out[(size_t)nIdx * F + (t << 2)] = o;
    }
}

// ----------------------------------------------------------------------------

extern "C" void kernel_launch(void* const* d_in, const int* in_sizes, int n_in,
                              void* d_out, int out_size, void* d_ws, size_t ws_size,
                              hipStream_t stream)
{
    const float* x   = (const float*)d_in[0];
    const int*   ei  = (const int*)d_in[1];
    const float* Wl1 = (const float*)d_in[2];
    const float* bl1 = (const float*)d_in[3];
    const float* Wr1 = (const float*)d_in[4];
    const float* br1 = (const float*)d_in[5];
    const float* at1 = (const float*)d_in[6];
    const float* b1  = (const float*)d_in[7];
    const float* Wl2 = (const float*)d_in[8];
    const float* bl2 = (const float*)d_in[9];
    const float* Wr2 = (const float*)d_in[10];
    const float* br2 = (const float*)d_in[11];
    const float* at2 = (const float*)d_in[12];
    const float* b2  = (const float*)d_in[13];
    const float* Wl3 = (const float*)d_in[14];
    const float* bl3 = (const float*)d_in[15];
    const float* Wr3 = (const float*)d_in[16];
    const float* br3 = (const float*)d_in[17];
    const float* at3 = (const float*)d_in[18];
    const float* b3  = (const float*)d_in[19];
    const float* Wc  = (const float*)d_in[20];
    const float* bc  = (const float*)d_in[21];

    const int N = in_sizes[0] / 128;       // 10000
    const int E_orig = in_sizes[1] / 2;    // 160000
    const int E_tot = E_orig + N;          // 170000

    // workspace carve (256B aligned)
    size_t off = 0;
    auto alloc = [&](size_t bytes) -> char* {
        char* p = (char*)d_ws + off;
        off += (bytes + 255) & ~(size_t)255;
        return p;
    };
    float* bufA   = (float*)alloc((size_t)N * 1024 * 4);  // xl (all layers)
    float* bufB   = (float*)alloc((size_t)N * 1024 * 4);  // xr1 -> h1 -> xr3 -> h3
    float* bufC   = (float*)alloc((size_t)N * 512 * 4);   // xr2 -> h2
    float* e_buf  = (float*)alloc((size_t)E_tot * 4);
    int* counts   = (int*)alloc((size_t)N * 4);
    int* offsets  = (int*)alloc((size_t)(N + 1) * 4);
    int* cursor   = (int*)alloc((size_t)N * 4);
    int* csr_src  = (int*)alloc((size_t)E_tot * 4);
    int* csr_eid  = (int*)alloc((size_t)E_tot * 4);
    (void)ws_size; (void)n_in; (void)out_size;

    const int eb = (E_tot + 255) / 256;

    // CSR by dst (edge_index constant across layers)
    zero_ints_kernel<<<(N + 255) / 256, 256, 0, stream>>>(counts, N);
    count_kernel<<<eb, 256, 0, stream>>>(ei, E_orig, E_tot, counts);
    scan_kernel<<<1, 256, 0, stream>>>(counts, N, offsets, cursor);
    fill_kernel<<<eb, 256, 0, stream>>>(ei, E_orig, E_tot, cursor, csr_src, csr_eid);

    const int elb = (E_tot + 3) / 4;
    const int mb = (N + BM - 1) / BM;

    // ---- layer 1: 128 -> 1024 ----
    gemm_bias_kernel<<<dim3(mb, 1024 / BN), 256, 0, stream>>>(x, Wl1, bl1, bufA, N, 128, 1024);
    gemm_bias_kernel<<<dim3(mb, 1024 / BN), 256, 0, stream>>>(x, Wr1, br1, bufB, N, 128, 1024);
    edge_logits_kernel<<<elb, 256, 0, stream>>>(bufA, bufB, at1, ei, E_orig, E_tot, 1024, e_buf);
    aggregate_kernel<<<N, 256, 0, stream>>>(bufA, e_buf, offsets, csr_src, csr_eid, b1, bufB, 1024);

    // ---- layer 2: 1024 -> 512 ----
    gemm_bias_kernel<<<dim3(mb, 512 / BN), 256, 0, stream>>>(bufB, Wl2, bl2, bufA, N, 1024, 512);
    gemm_bias_kernel<<<dim3(mb, 512 / BN), 256, 0, stream>>>(bufB, Wr2, br2, bufC, N, 1024, 512);
    edge_logits_kernel<<<elb, 256, 0, stream>>>(bufA, bufC, at2, ei, E_orig, E_tot, 512, e_buf);
    aggregate_kernel<<<N, 256, 0, stream>>>(bufA, e_buf, offsets, csr_src, csr_eid, b2, bufC, 512);

    // ---- layer 3: 512 -> 128 ----
    gemm_bias_kernel<<<dim3(mb, 128 / BN), 256, 0, stream>>>(bufC, Wl3, bl3, bufA, N, 512, 128);
    gemm_bias_kernel<<<dim3(mb, 128 / BN), 256, 0, stream>>>(bufC, Wr3, br3, bufB, N, 512, 128);
    edge_logits_kernel<<<elb, 256, 0, stream>>>(bufA, bufB, at3, ei, E_orig, E_tot, 128, e_buf);
    aggregate_kernel<<<N, 256, 0, stream>>>(bufA, e_buf, offsets, csr_src, csr_eid, b3, bufB, 128);

    // ---- classifier: 128 -> 64 ----
    gemm_bias_kernel<<<dim3(mb, 64 / BN), 256, 0, stream>>>(bufB, Wc, bc, (float*)d_out, N, 128, 64);
}

// Round 2
// 697.710 us; speedup vs baseline: 1.4332x; 1.4332x over previous
//
#include <hip/hip_runtime.h>

// ---------------------------------------------------------------------------
// 3-layer GATv2 + classifier on MI355X. f32 everywhere.
// Per layer: xl = h@Wl+bl, xr = h@Wr+br (tiled f32 GEMM), then a FUSED
// per-dst-node kernel: online-softmax over in-edges computing logits
// e = lrelu(xl[src]+xr[dst])@att and the weighted sum in ONE pass over
// xl[src] rows (1 row-gather per edge instead of 3).
// ---------------------------------------------------------------------------

static constexpr int BM = 64, BN = 64, BK = 16;

__global__ __launch_bounds__(256) void gemm_bias_kernel(
    const float* __restrict__ A, const float* __restrict__ W,
    const float* __restrict__ bias, float* __restrict__ C,
    int M, int K, int F)
{
    __shared__ float As[BK][BM];
    __shared__ float Bs[BK][BN];
    const int t = threadIdx.x;
    const int bm = blockIdx.x, bn = blockIdx.y;
    const int ty = t >> 4, tx = t & 15;          // 16x16 threads, each 4x4 out
    const int rowBase = bm * BM;
    const int colBase = bn * BN;
    const int aRow = t & 63;                     // A tile: 64 rows x 16 k
    const int aK = (t >> 6) << 2;
    const int gARow = min(rowBase + aRow, M - 1);
    const int bRow = t >> 4;                     // B tile: 16 rows x 64 cols
    const int bCol = (t & 15) << 2;

    float acc[4][4] = {{0.f, 0.f, 0.f, 0.f}};

    for (int k0 = 0; k0 < K; k0 += BK) {
        float4 av = *(const float4*)&A[(size_t)gARow * K + k0 + aK];
        float4 bv = *(const float4*)&W[(size_t)(k0 + bRow) * F + colBase + bCol];
        As[aK + 0][aRow] = av.x;
        As[aK + 1][aRow] = av.y;
        As[aK + 2][aRow] = av.z;
        As[aK + 3][aRow] = av.w;
        *(float4*)&Bs[bRow][bCol] = bv;
        __syncthreads();
#pragma unroll
        for (int kk = 0; kk < BK; ++kk) {
            float4 a4 = *(const float4*)&As[kk][ty << 2];
            float4 b4 = *(const float4*)&Bs[kk][tx << 2];
            float ar[4] = {a4.x, a4.y, a4.z, a4.w};
            float br_[4] = {b4.x, b4.y, b4.z, b4.w};
#pragma unroll
            for (int i = 0; i < 4; ++i)
#pragma unroll
                for (int j = 0; j < 4; ++j)
                    acc[i][j] += ar[i] * br_[j];
        }
        __syncthreads();
    }

    float4 bias4 = *(const float4*)&bias[colBase + (tx << 2)];
    float bb[4] = {bias4.x, bias4.y, bias4.z, bias4.w};
#pragma unroll
    for (int i = 0; i < 4; ++i) {
        int r = rowBase + (ty << 2) + i;
        if (r < M) {
            float4 o;
            o.x = acc[i][0] + bb[0];
            o.y = acc[i][1] + bb[1];
            o.z = acc[i][2] + bb[2];
            o.w = acc[i][3] + bb[3];
            *(float4*)&C[(size_t)r * F + colBase + (tx << 2)] = o;
        }
    }
}

// --------------------------- CSR build kernels ------------------------------

__global__ void zero_ints_kernel(int* __restrict__ p, int n)
{
    int i = blockIdx.x * blockDim.x + threadIdx.x;
    if (i < n) p[i] = 0;
}

__device__ inline void edge_src_dst(const int* __restrict__ ei, int edge,
                                    int E_orig, int& src, int& dst)
{
    if (edge < E_orig) {
        src = ei[edge];
        dst = ei[E_orig + edge];
    } else {
        src = dst = edge - E_orig;   // self-loop
    }
}

__global__ void count_kernel(const int* __restrict__ ei, int E_orig, int E_tot,
                             int* __restrict__ counts)
{
    int e = blockIdx.x * blockDim.x + threadIdx.x;
    if (e >= E_tot) return;
    int src, dst;
    edge_src_dst(ei, e, E_orig, src, dst);
    atomicAdd(&counts[dst], 1);
}

__global__ __launch_bounds__(256) void scan_kernel(const int* __restrict__ counts, int n,
                                                   int* __restrict__ offsets,
                                                   int* __restrict__ cursor)
{
    __shared__ int part[256];
    const int t = threadIdx.x;
    const int chunk = (n + 255) >> 8;
    const int begin = t * chunk;
    const int end = min(begin + chunk, n);
    int s = 0;
    for (int i = begin; i < end; ++i) s += counts[i];
    part[t] = s;
    __syncthreads();
    for (int off = 1; off < 256; off <<= 1) {
        int v = (t >= off) ? part[t - off] : 0;
        __syncthreads();
        part[t] += v;
        __syncthreads();
    }
    int run = (t == 0) ? 0 : part[t - 1];
    for (int i = begin; i < end; ++i) {
        offsets[i] = run;
        cursor[i] = run;
        run += counts[i];
    }
    if (t == 255) offsets[n] = part[255];
}

__global__ void fill_kernel(const int* __restrict__ ei, int E_orig, int E_tot,
                            int* __restrict__ cursor, int* __restrict__ csr_src)
{
    int e = blockIdx.x * blockDim.x + threadIdx.x;
    if (e >= E_tot) return;
    int src, dst;
    edge_src_dst(ei, e, E_orig, src, dst);
    int pos = atomicAdd(&cursor[dst], 1);
    csr_src[pos] = src;
}

// ---------------- fused logits + online-softmax + aggregate -----------------
// One block per dst node. NTHREADS = F/VEC threads each own VEC features.
// Online softmax over in-edges; xl[src] row read exactly once per edge.

template<int F, int NTHREADS>
__global__ __launch_bounds__(NTHREADS) void fused_gat_kernel(
    const float* __restrict__ xl, const float* __restrict__ xr,
    const float* __restrict__ att, const int* __restrict__ offsets,
    const int* __restrict__ csr_src, const float* __restrict__ bias,
    float* __restrict__ out)
{
    constexpr int VEC = F / NTHREADS;        // 4 (F=1024,512) or 2 (F=128)
    constexpr int NW = NTHREADS / 64;        // waves per block
    const int n = blockIdx.x;
    const int t = threadIdx.x;
    const int start = offsets[n], end = offsets[n + 1];

    __shared__ float wsum[2][NW > 1 ? NW : 1];

    // stage xr[n], att slices in registers
    float xr_r[VEC], att_r[VEC], acc[VEC];
#pragma unroll
    for (int v = 0; v < VEC; ++v) {
        xr_r[v]  = xr[(size_t)n * F + t * VEC + v];
        att_r[v] = att[t * VEC + v];
        acc[v]   = 0.f;
    }

    float m = -1e30f, d = 0.f;
    int parity = 0;

    for (int i = start; i < end; ++i, parity ^= 1) {
        const int src = csr_src[i];
        const float* row = xl + (size_t)src * F + t * VEC;
        float xlv[VEC];
        if constexpr (VEC == 4) {
            float4 v4 = *(const float4*)row;
            xlv[0] = v4.x; xlv[1] = v4.y; xlv[2] = v4.z; xlv[3] = v4.w;
        } else {
            float2 v2 = *(const float2*)row;
            xlv[0] = v2.x; xlv[1] = v2.y;
        }
        // per-thread partial of logit
        float p = 0.f;
#pragma unroll
        for (int v = 0; v < VEC; ++v) {
            float mm = xlv[v] + xr_r[v];
            mm = (mm >= 0.f) ? mm : 0.2f * mm;
            p += mm * att_r[v];
        }
        // wave reduce (64 lanes)
#pragma unroll
        for (int off = 32; off; off >>= 1) p += __shfl_xor(p, off);
        float e;
        if constexpr (NW > 1) {
            if ((t & 63) == 0) wsum[parity][t >> 6] = p;
            __syncthreads();
            e = wsum[parity][0];
#pragma unroll
            for (int w = 1; w < NW; ++w) e += wsum[parity][w];
        } else {
            e = p;
        }
        // online softmax update
        const float nm = fmaxf(m, e);
        const float scale = __expf(m - nm);   // first iter: exp(-huge)=0
        const float wgt = __expf(e - nm);
        d = d * scale + wgt;
#pragma unroll
        for (int v = 0; v < VEC; ++v) acc[v] = acc[v] * scale + wgt * xlv[v];
        m = nm;
    }

    const float inv = 1.0f / d;
#pragma unroll
    for (int v = 0; v < VEC; ++v) {
        float o = acc[v] * inv + bias[t * VEC + v];
        out[(size_t)n * F + t * VEC + v] = fmaxf(o, 0.f);
    }
}

// ----------------------------------------------------------------------------

extern "C" void kernel_launch(void* const* d_in, const int* in_sizes, int n_in,
                              void* d_out, int out_size, void* d_ws, size_t ws_size,
                              hipStream_t stream)
{
    const float* x   = (const float*)d_in[0];
    const int*   ei  = (const int*)d_in[1];
    const float* Wl1 = (const float*)d_in[2];
    const float* bl1 = (const float*)d_in[3];
    const float* Wr1 = (const float*)d_in[4];
    const float* br1 = (const float*)d_in[5];
    const float* at1 = (const float*)d_in[6];
    const float* b1  = (const float*)d_in[7];
    const float* Wl2 = (const float*)d_in[8];
    const float* bl2 = (const float*)d_in[9];
    const float* Wr2 = (const float*)d_in[10];
    const float* br2 = (const float*)d_in[11];
    const float* at2 = (const float*)d_in[12];
    const float* b2  = (const float*)d_in[13];
    const float* Wl3 = (const float*)d_in[14];
    const float* bl3 = (const float*)d_in[15];
    const float* Wr3 = (const float*)d_in[16];
    const float* br3 = (const float*)d_in[17];
    const float* at3 = (const float*)d_in[18];
    const float* b3  = (const float*)d_in[19];
    const float* Wc  = (const float*)d_in[20];
    const float* bc  = (const float*)d_in[21];

    const int N = in_sizes[0] / 128;       // 10000
    const int E_orig = in_sizes[1] / 2;    // 160000
    const int E_tot = E_orig + N;          // 170000

    // workspace carve (256B aligned)
    size_t off = 0;
    auto alloc = [&](size_t bytes) -> char* {
        char* p = (char*)d_ws + off;
        off += (bytes + 255) & ~(size_t)255;
        return p;
    };
    float* bufA   = (float*)alloc((size_t)N * 1024 * 4);  // xl (all layers)
    float* bufB   = (float*)alloc((size_t)N * 1024 * 4);  // xr1 -> h1 -> xr3 -> h3
    float* bufC   = (float*)alloc((size_t)N * 512 * 4);   // xr2 -> h2
    int* counts   = (int*)alloc((size_t)N * 4);
    int* offsets  = (int*)alloc((size_t)(N + 1) * 4);
    int* cursor   = (int*)alloc((size_t)N * 4);
    int* csr_src  = (int*)alloc((size_t)E_tot * 4);
    (void)ws_size; (void)n_in; (void)out_size;

    const int eb = (E_tot + 255) / 256;

    // CSR by dst (edge_index constant across layers)
    zero_ints_kernel<<<(N + 255) / 256, 256, 0, stream>>>(counts, N);
    count_kernel<<<eb, 256, 0, stream>>>(ei, E_orig, E_tot, counts);
    scan_kernel<<<1, 256, 0, stream>>>(counts, N, offsets, cursor);
    fill_kernel<<<eb, 256, 0, stream>>>(ei, E_orig, E_tot, cursor, csr_src);

    const int mb = (N + BM - 1) / BM;

    // ---- layer 1: 128 -> 1024 ----
    gemm_bias_kernel<<<dim3(mb, 1024 / BN), 256, 0, stream>>>(x, Wl1, bl1, bufA, N, 128, 1024);
    gemm_bias_kernel<<<dim3(mb, 1024 / BN), 256, 0, stream>>>(x, Wr1, br1, bufB, N, 128, 1024);
    fused_gat_kernel<1024, 256><<<N, 256, 0, stream>>>(bufA, bufB, at1, offsets, csr_src, b1, bufB);

    // ---- layer 2: 1024 -> 512 ----
    gemm_bias_kernel<<<dim3(mb, 512 / BN), 256, 0, stream>>>(bufB, Wl2, bl2, bufA, N, 1024, 512);
    gemm_bias_kernel<<<dim3(mb, 512 / BN), 256, 0, stream>>>(bufB, Wr2, br2, bufC, N, 1024, 512);
    fused_gat_kernel<512, 128><<<N, 128, 0, stream>>>(bufA, bufC, at2, offsets, csr_src, b2, bufC);

    // ---- layer 3: 512 -> 128 ----
    gemm_bias_kernel<<<dim3(mb, 128 / BN), 256, 0, stream>>>(bufC, Wl3, bl3, bufA, N, 512, 128);
    gemm_bias_kernel<<<dim3(mb, 128 / BN), 256, 0, stream>>>(bufC, Wr3, br3, bufB, N, 512, 128);
    fused_gat_kernel<128, 64><<<N, 64, 0, stream>>>(bufA, bufB, at3, offsets, csr_src, b3, bufB);

    // ---- classifier: 128 -> 64 ----
    gemm_bias_kernel<<<dim3(mb, 64 / BN), 256, 0, stream>>>(bufB, Wc, bc, (float*)d_out, N, 128, 64);
}

// Round 3
// 449.216 us; speedup vs baseline: 2.2260x; 1.5532x over previous
//
#include <hip/hip_runtime.h>

// ---------------------------------------------------------------------------
// 3-layer GATv2 + classifier on MI355X.
// GEMMs: bf16x3 split-precision MFMA (hi*hi + hi*lo + lo*hi), 128x128x32 tile,
// global_load_lds staging, f32 accumulate -> ~f32 accuracy at matrix-core rate.
// Activations live as bf16 hi/lo pairs (written by the fused GAT epilogue).
// Fused GAT: online-softmax over in-edges, 1 row-gather per edge.
// ---------------------------------------------------------------------------

typedef __attribute__((ext_vector_type(8))) short bf16x8;
typedef __attribute__((ext_vector_type(4))) float f32x4;

__device__ __forceinline__ unsigned short bf16rn(float x) {
    union { float f; unsigned int u; } v; v.f = x;
    unsigned int r = v.u + 0x7FFF + ((v.u >> 16) & 1);
    return (unsigned short)(r >> 16);
}
__device__ __forceinline__ float bf16tof(unsigned short h) {
    union { unsigned int u; float f; } v; v.u = ((unsigned int)h) << 16;
    return v.f;
}

typedef __attribute__((address_space(1))) const void* gptr_t;
typedef __attribute__((address_space(3))) void* sptr_t;
__device__ __forceinline__ void gload_lds16(const void* g, void* l) {
    __builtin_amdgcn_global_load_lds((gptr_t)g, (sptr_t)l, 16, 0, 0);
}

// ------------------------- weight split + transpose -------------------------
// W [K,F] f32 -> Th, Tl [F,K] bf16 (hi, residual-lo). K,F multiples of 32.

__global__ __launch_bounds__(256) void splitT_kernel(
    const float* __restrict__ W, unsigned short* __restrict__ Th,
    unsigned short* __restrict__ Tl, int K, int F)
{
    __shared__ float tile[32][33];
    const int tx = threadIdx.x & 31, ty = threadIdx.x >> 5;
    const int k0 = blockIdx.x * 32, f0 = blockIdx.y * 32;
#pragma unroll
    for (int i = 0; i < 32; i += 8)
        tile[ty + i][tx] = W[(size_t)(k0 + ty + i) * F + f0 + tx];
    __syncthreads();
#pragma unroll
    for (int i = 0; i < 32; i += 8) {
        int f = f0 + ty + i, k = k0 + tx;
        float v = tile[tx][ty + i];
        unsigned short h = bf16rn(v);
        Th[(size_t)f * K + k] = h;
        Tl[(size_t)f * K + k] = bf16rn(v - bf16tof(h));
    }
}

// x [n4*4] f32 -> hi, lo bf16 same layout
__global__ void split_kernel(const float* __restrict__ X,
                             unsigned short* __restrict__ Hi,
                             unsigned short* __restrict__ Lo, int n4)
{
    int i = blockIdx.x * blockDim.x + threadIdx.x;
    if (i >= n4) return;
    float4 v = ((const float4*)X)[i];
    ushort4 h, l;
    h.x = bf16rn(v.x); l.x = bf16rn(v.x - bf16tof(h.x));
    h.y = bf16rn(v.y); l.y = bf16rn(v.y - bf16tof(h.y));
    h.z = bf16rn(v.z); l.z = bf16rn(v.z - bf16tof(h.z));
    h.w = bf16rn(v.w); l.w = bf16rn(v.w - bf16tof(h.w));
    ((ushort4*)Hi)[i] = h;
    ((ushort4*)Lo)[i] = l;
}

// ------------------- bf16x3 MFMA GEMM, fused l/r weights --------------------
// A: bf16 hi/lo [M,K]. WT*: bf16 [F,K] (W^T). C = A@W + bias, f32 out.
// blockIdx.y < F/128 -> "A" weight set, else "B" set. 128x128 tile, 4 waves.

__global__ __launch_bounds__(256) void gemm2_mfma_kernel(
    const unsigned short* __restrict__ Ahi, const unsigned short* __restrict__ Alo,
    int M, int K,
    const unsigned short* __restrict__ WThA, const unsigned short* __restrict__ WTlA,
    const unsigned short* __restrict__ WThB, const unsigned short* __restrict__ WTlB,
    const float* __restrict__ biasA, const float* __restrict__ biasB,
    float* __restrict__ CA, float* __restrict__ CB, int F)
{
    __shared__ unsigned short Ash[128 * 32];
    __shared__ unsigned short Asl[128 * 32];
    __shared__ unsigned short Bsh[128 * 32];
    __shared__ unsigned short Bsl[128 * 32];

    const int t = threadIdx.x;
    const int lane = t & 63, wave = t >> 6;
    const int nyh = (int)gridDim.y >> 1;
    const int half = ((int)blockIdx.y >= nyh) ? 1 : 0;
    const int colBase = ((int)blockIdx.y - half * nyh) * 128;
    const unsigned short* WTh = half ? WThB : WThA;
    const unsigned short* WTl = half ? WTlB : WTlA;
    const float* bias = half ? biasB : biasA;
    float* C = half ? CB : CA;
    const int rowBase = (int)blockIdx.x * 128;

    const int wr = wave >> 1, wc = wave & 1;
    const int fr = lane & 15, g = lane >> 4;

    // staging addresses: wave stages tile rows [wave*16, +16) and [(wave+4)*16, +16)
    const int srow = lane >> 2;              // 0..15
    const int schunk = (lane & 3) * 8;       // ushort offset (16B chunks)
    const int r0 = wave * 16 + srow;
    const int r1 = (wave + 4) * 16 + srow;
    int ga0 = rowBase + r0; if (ga0 > M - 1) ga0 = M - 1;
    int ga1 = rowBase + r1; if (ga1 > M - 1) ga1 = M - 1;

    const unsigned short* pAh0 = Ahi + (size_t)ga0 * K + schunk;
    const unsigned short* pAh1 = Ahi + (size_t)ga1 * K + schunk;
    const unsigned short* pAl0 = Alo + (size_t)ga0 * K + schunk;
    const unsigned short* pAl1 = Alo + (size_t)ga1 * K + schunk;
    const unsigned short* pBh0 = WTh + (size_t)(colBase + r0) * K + schunk;
    const unsigned short* pBh1 = WTh + (size_t)(colBase + r1) * K + schunk;
    const unsigned short* pBl0 = WTl + (size_t)(colBase + r0) * K + schunk;
    const unsigned short* pBl1 = WTl + (size_t)(colBase + r1) * K + schunk;

    unsigned short* dAh0 = &Ash[wave * 512];
    unsigned short* dAh1 = &Ash[(wave + 4) * 512];
    unsigned short* dAl0 = &Asl[wave * 512];
    unsigned short* dAl1 = &Asl[(wave + 4) * 512];
    unsigned short* dBh0 = &Bsh[wave * 512];
    unsigned short* dBh1 = &Bsh[(wave + 4) * 512];
    unsigned short* dBl0 = &Bsl[wave * 512];
    unsigned short* dBl1 = &Bsl[(wave + 4) * 512];

    f32x4 acc[4][4];
#pragma unroll
    for (int i = 0; i < 4; ++i)
#pragma unroll
        for (int j = 0; j < 4; ++j) acc[i][j] = (f32x4)(0.f);

    for (int k0 = 0; k0 < K; k0 += 32) {
        gload_lds16(pAh0 + k0, dAh0);
        gload_lds16(pAh1 + k0, dAh1);
        gload_lds16(pAl0 + k0, dAl0);
        gload_lds16(pAl1 + k0, dAl1);
        gload_lds16(pBh0 + k0, dBh0);
        gload_lds16(pBh1 + k0, dBh1);
        gload_lds16(pBl0 + k0, dBl0);
        gload_lds16(pBl1 + k0, dBl1);
        __syncthreads();

        bf16x8 ah[4], al[4], bh[4], bl[4];
#pragma unroll
        for (int mi = 0; mi < 4; ++mi) {
            ah[mi] = *(const bf16x8*)&Ash[(wr * 64 + mi * 16 + fr) * 32 + g * 8];
            al[mi] = *(const bf16x8*)&Asl[(wr * 64 + mi * 16 + fr) * 32 + g * 8];
        }
#pragma unroll
        for (int ni = 0; ni < 4; ++ni) {
            bh[ni] = *(const bf16x8*)&Bsh[(wc * 64 + ni * 16 + fr) * 32 + g * 8];
            bl[ni] = *(const bf16x8*)&Bsl[(wc * 64 + ni * 16 + fr) * 32 + g * 8];
        }
#pragma unroll
        for (int mi = 0; mi < 4; ++mi)
#pragma unroll
            for (int ni = 0; ni < 4; ++ni) {
                acc[mi][ni] = __builtin_amdgcn_mfma_f32_16x16x32_bf16(ah[mi], bh[ni], acc[mi][ni], 0, 0, 0);
                acc[mi][ni] = __builtin_amdgcn_mfma_f32_16x16x32_bf16(ah[mi], bl[ni], acc[mi][ni], 0, 0, 0);
                acc[mi][ni] = __builtin_amdgcn_mfma_f32_16x16x32_bf16(al[mi], bh[ni], acc[mi][ni], 0, 0, 0);
            }
        __syncthreads();
    }

#pragma unroll
    for (int mi = 0; mi < 4; ++mi) {
        const int row0 = rowBase + wr * 64 + mi * 16 + g * 4;
#pragma unroll
        for (int ni = 0; ni < 4; ++ni) {
            const int col = colBase + wc * 64 + ni * 16 + fr;
            const float b = bias[col];
#pragma unroll
            for (int r = 0; r < 4; ++r) {
                const int row = row0 + r;
                if (row < M) C[(size_t)row * F + col] = acc[mi][ni][r] + b;
            }
        }
    }
}

// --------------------------- f32 classifier GEMM ----------------------------

static constexpr int BM = 64, BN = 64, BK = 16;

__global__ __launch_bounds__(256) void gemm_bias_kernel(
    const float* __restrict__ A, const float* __restrict__ W,
    const float* __restrict__ bias, float* __restrict__ C,
    int M, int K, int F)
{
    __shared__ float As[BK][BM];
    __shared__ float Bs[BK][BN];
    const int t = threadIdx.x;
    const int bm = blockIdx.x, bn = blockIdx.y;
    const int ty = t >> 4, tx = t & 15;
    const int rowBase = bm * BM;
    const int colBase = bn * BN;
    const int aRow = t & 63;
    const int aK = (t >> 6) << 2;
    const int gARow = min(rowBase + aRow, M - 1);
    const int bRow = t >> 4;
    const int bCol = (t & 15) << 2;

    float acc[4][4] = {{0.f, 0.f, 0.f, 0.f}};

    for (int k0 = 0; k0 < K; k0 += BK) {
        float4 av = *(const float4*)&A[(size_t)gARow * K + k0 + aK];
        float4 bv = *(const float4*)&W[(size_t)(k0 + bRow) * F + colBase + bCol];
        As[aK + 0][aRow] = av.x;
        As[aK + 1][aRow] = av.y;
        As[aK + 2][aRow] = av.z;
        As[aK + 3][aRow] = av.w;
        *(float4*)&Bs[bRow][bCol] = bv;
        __syncthreads();
#pragma unroll
        for (int kk = 0; kk < BK; ++kk) {
            float4 a4 = *(const float4*)&As[kk][ty << 2];
            float4 b4 = *(const float4*)&Bs[kk][tx << 2];
            float ar[4] = {a4.x, a4.y, a4.z, a4.w};
            float br_[4] = {b4.x, b4.y, b4.z, b4.w};
#pragma unroll
            for (int i = 0; i < 4; ++i)
#pragma unroll
                for (int j = 0; j < 4; ++j)
                    acc[i][j] += ar[i] * br_[j];
        }
        __syncthreads();
    }

    float4 bias4 = *(const float4*)&bias[colBase + (tx << 2)];
    float bb[4] = {bias4.x, bias4.y, bias4.z, bias4.w};
#pragma unroll
    for (int i = 0; i < 4; ++i) {
        int r = rowBase + (ty << 2) + i;
        if (r < M) {
            float4 o;
            o.x = acc[i][0] + bb[0];
            o.y = acc[i][1] + bb[1];
            o.z = acc[i][2] + bb[2];
            o.w = acc[i][3] + bb[3];
            *(float4*)&C[(size_t)r * F + colBase + (tx << 2)] = o;
        }
    }
}

// --------------------------- CSR build kernels ------------------------------

__global__ void zero_ints_kernel(int* __restrict__ p, int n)
{
    int i = blockIdx.x * blockDim.x + threadIdx.x;
    if (i < n) p[i] = 0;
}

__device__ inline void edge_src_dst(const int* __restrict__ ei, int edge,
                                    int E_orig, int& src, int& dst)
{
    if (edge < E_orig) {
        src = ei[edge];
        dst = ei[E_orig + edge];
    } else {
        src = dst = edge - E_orig;   // self-loop
    }
}

__global__ void count_kernel(const int* __restrict__ ei, int E_orig, int E_tot,
                             int* __restrict__ counts)
{
    int e = blockIdx.x * blockDim.x + threadIdx.x;
    if (e >= E_tot) return;
    int src, dst;
    edge_src_dst(ei, e, E_orig, src, dst);
    atomicAdd(&counts[dst], 1);
}

__global__ __launch_bounds__(256) void scan_kernel(const int* __restrict__ counts, int n,
                                                   int* __restrict__ offsets,
                                                   int* __restrict__ cursor)
{
    __shared__ int part[256];
    const int t = threadIdx.x;
    const int chunk = (n + 255) >> 8;
    const int begin = t * chunk;
    const int end = min(begin + chunk, n);
    int s = 0;
    for (int i = begin; i < end; ++i) s += counts[i];
    part[t] = s;
    __syncthreads();
    for (int off = 1; off < 256; off <<= 1) {
        int v = (t >= off) ? part[t - off] : 0;
        __syncthreads();
        part[t] += v;
        __syncthreads();
    }
    int run = (t == 0) ? 0 : part[t - 1];
    for (int i = begin; i < end; ++i) {
        offsets[i] = run;
        cursor[i] = run;
        run += counts[i];
    }
    if (t == 255) offsets[n] = part[255];
}

__global__ void fill_kernel(const int* __restrict__ ei, int E_orig, int E_tot,
                            int* __restrict__ cursor, int* __restrict__ csr_src)
{
    int e = blockIdx.x * blockDim.x + threadIdx.x;
    if (e >= E_tot) return;
    int src, dst;
    edge_src_dst(ei, e, E_orig, src, dst);
    int pos = atomicAdd(&cursor[dst], 1);
    csr_src[pos] = src;
}

// ---------------- fused logits + online-softmax + aggregate -----------------
// One block per dst node. Optionally writes f32 output and/or bf16 hi/lo split.

template<int F, int NTHREADS>
__global__ __launch_bounds__(NTHREADS) void fused_gat_kernel(
    const float* __restrict__ xl, const float* __restrict__ xr,
    const float* __restrict__ att, const int* __restrict__ offsets,
    const int* __restrict__ csr_src, const float* __restrict__ bias,
    float* __restrict__ out_f32,
    unsigned short* __restrict__ out_hi, unsigned short* __restrict__ out_lo)
{
    constexpr int VEC = F / NTHREADS;        // 4 (F=1024,512) or 2 (F=128)
    constexpr int NW = NTHREADS / 64;        // waves per block
    const int n = blockIdx.x;
    const int t = threadIdx.x;
    const int start = offsets[n], end = offsets[n + 1];

    __shared__ float wsum[2][NW > 1 ? NW : 1];

    float xr_r[VEC], att_r[VEC], acc[VEC];
#pragma unroll
    for (int v = 0; v < VEC; ++v) {
        xr_r[v]  = xr[(size_t)n * F + t * VEC + v];
        att_r[v] = att[t * VEC + v];
        acc[v]   = 0.f;
    }

    float m = -1e30f, d = 0.f;
    int parity = 0;

    for (int i = start; i < end; ++i, parity ^= 1) {
        const int src = csr_src[i];
        const float* row = xl + (size_t)src * F + t * VEC;
        float xlv[VEC];
        if constexpr (VEC == 4) {
            float4 v4 = *(const float4*)row;
            xlv[0] = v4.x; xlv[1] = v4.y; xlv[2] = v4.z; xlv[3] = v4.w;
        } else {
            float2 v2 = *(const float2*)row;
            xlv[0] = v2.x; xlv[1] = v2.y;
        }
        float p = 0.f;
#pragma unroll
        for (int v = 0; v < VEC; ++v) {
            float mm = xlv[v] + xr_r[v];
            mm = (mm >= 0.f) ? mm : 0.2f * mm;
            p += mm * att_r[v];
        }
#pragma unroll
        for (int off = 32; off; off >>= 1) p += __shfl_xor(p, off);
        float e;
        if constexpr (NW > 1) {
            if ((t & 63) == 0) wsum[parity][t >> 6] = p;
            __syncthreads();
            e = wsum[parity][0];
#pragma unroll
            for (int w = 1; w < NW; ++w) e += wsum[parity][w];
        } else {
            e = p;
        }
        const float nm = fmaxf(m, e);
        const float scale = __expf(m - nm);
        const float wgt = __expf(e - nm);
        d = d * scale + wgt;
#pragma unroll
        for (int v = 0; v < VEC; ++v) acc[v] = acc[v] * scale + wgt * xlv[v];
        m = nm;
    }

    const float inv = 1.0f / d;
#pragma unroll
    for (int v = 0; v < VEC; ++v) {
        const size_t idx = (size_t)n * F + t * VEC + v;
        float o = fmaxf(acc[v] * inv + bias[t * VEC + v], 0.f);
        if (out_f32) out_f32[idx] = o;
        if (out_hi) {
            unsigned short h = bf16rn(o);
            out_hi[idx] = h;
            out_lo[idx] = bf16rn(o - bf16tof(h));
        }
    }
}

// ----------------------------------------------------------------------------

extern "C" void kernel_launch(void* const* d_in, const int* in_sizes, int n_in,
                              void* d_out, int out_size, void* d_ws, size_t ws_size,
                              hipStream_t stream)
{
    const float* x   = (const float*)d_in[0];
    const int*   ei  = (const int*)d_in[1];
    const float* Wl1 = (const float*)d_in[2];
    const float* bl1 = (const float*)d_in[3];
    const float* Wr1 = (const float*)d_in[4];
    const float* br1 = (const float*)d_in[5];
    const float* at1 = (const float*)d_in[6];
    const float* b1  = (const float*)d_in[7];
    const float* Wl2 = (const float*)d_in[8];
    const float* bl2 = (const float*)d_in[9];
    const float* Wr2 = (const float*)d_in[10];
    const float* br2 = (const float*)d_in[11];
    const float* at2 = (const float*)d_in[12];
    const float* b2  = (const float*)d_in[13];
    const float* Wl3 = (const float*)d_in[14];
    const float* bl3 = (const float*)d_in[15];
    const float* Wr3 = (const float*)d_in[16];
    const float* br3 = (const float*)d_in[17];
    const float* at3 = (const float*)d_in[18];
    const float* b3  = (const float*)d_in[19];
    const float* Wc  = (const float*)d_in[20];
    const float* bc  = (const float*)d_in[21];

    const int N = in_sizes[0] / 128;       // 10000
    const int E_orig = in_sizes[1] / 2;    // 160000
    const int E_tot = E_orig + N;          // 170000

    size_t off = 0;
    auto alloc = [&](size_t bytes) -> char* {
        char* p = (char*)d_ws + off;
        off += (bytes + 255) & ~(size_t)255;
        return p;
    };
    float* bufA = (float*)alloc((size_t)N * 1024 * 4);          // xl (f32)
    float* bufB = (float*)alloc((size_t)N * 1024 * 4);          // xr (f32), h3 in-place
    unsigned short* S_hi = (unsigned short*)alloc((size_t)N * 1024 * 2);  // x/h split hi
    unsigned short* S_lo = (unsigned short*)alloc((size_t)N * 1024 * 2);  // x/h split lo
    unsigned short* WThl = (unsigned short*)alloc((size_t)524288 * 2);
    unsigned short* WTll = (unsigned short*)alloc((size_t)524288 * 2);
    unsigned short* WThr = (unsigned short*)alloc((size_t)524288 * 2);
    unsigned short* WTlr = (unsigned short*)alloc((size_t)524288 * 2);
    int* counts  = (int*)alloc((size_t)N * 4);
    int* offsets = (int*)alloc((size_t)(N + 1) * 4);
    int* cursor  = (int*)alloc((size_t)N * 4);
    int* csr_src = (int*)alloc((size_t)E_tot * 4);
    (void)ws_size; (void)n_in; (void)out_size;

    const int eb = (E_tot + 255) / 256;
    const int mb128 = (N + 127) / 128;     // 79

    // CSR by dst (edge_index constant across layers)
    zero_ints_kernel<<<(N + 255) / 256, 256, 0, stream>>>(counts, N);
    count_kernel<<<eb, 256, 0, stream>>>(ei, E_orig, E_tot, counts);
    scan_kernel<<<1, 256, 0, stream>>>(counts, N, offsets, cursor);
    fill_kernel<<<eb, 256, 0, stream>>>(ei, E_orig, E_tot, cursor, csr_src);

    // split input x -> S (bf16 hi/lo)
    split_kernel<<<(N * 128 / 4 + 255) / 256, 256, 0, stream>>>(x, S_hi, S_lo, N * 128 / 4);

    // ---- layer 1: 128 -> 1024 ----
    splitT_kernel<<<dim3(128 / 32, 1024 / 32), 256, 0, stream>>>(Wl1, WThl, WTll, 128, 1024);
    splitT_kernel<<<dim3(128 / 32, 1024 / 32), 256, 0, stream>>>(Wr1, WThr, WTlr, 128, 1024);
    gemm2_mfma_kernel<<<dim3(mb128, 16), 256, 0, stream>>>(
        S_hi, S_lo, N, 128, WThl, WTll, WThr, WTlr, bl1, br1, bufA, bufB, 1024);
    fused_gat_kernel<1024, 256><<<N, 256, 0, stream>>>(
        bufA, bufB, at1, offsets, csr_src, b1, nullptr, S_hi, S_lo);

    // ---- layer 2: 1024 -> 512 ----
    splitT_kernel<<<dim3(1024 / 32, 512 / 32), 256, 0, stream>>>(Wl2, WThl, WTll, 1024, 512);
    splitT_kernel<<<dim3(1024 / 32, 512 / 32), 256, 0, stream>>>(Wr2, WThr, WTlr, 1024, 512);
    gemm2_mfma_kernel<<<dim3(mb128, 8), 256, 0, stream>>>(
        S_hi, S_lo, N, 1024, WThl, WTll, WThr, WTlr, bl2, br2, bufA, bufB, 512);
    fused_gat_kernel<512, 128><<<N, 128, 0, stream>>>(
        bufA, bufB, at2, offsets, csr_src, b2, nullptr, S_hi, S_lo);

    // ---- layer 3: 512 -> 128 ----
    splitT_kernel<<<dim3(512 / 32, 128 / 32), 256, 0, stream>>>(Wl3, WThl, WTll, 512, 128);
    splitT_kernel<<<dim3(512 / 32, 128 / 32), 256, 0, stream>>>(Wr3, WThr, WTlr, 512, 128);
    gemm2_mfma_kernel<<<dim3(mb128, 2), 256, 0, stream>>>(
        S_hi, S_lo, N, 512, WThl, WTll, WThr, WTlr, bl3, br3, bufA, bufB, 128);
    fused_gat_kernel<128, 64><<<N, 64, 0, stream>>>(
        bufA, bufB, at3, offsets, csr_src, b3, bufB, nullptr, nullptr);

    // ---- classifier: 128 -> 64 (f32 vector GEMM) ----
    gemm_bias_kernel<<<dim3((N + BM - 1) / BM, 64 / BN), 256, 0, stream>>>(
        bufB, Wc, bc, (float*)d_out, N, 128, 64);
}